// Round 2
// baseline (308.012 us; speedup 1.0000x reference)
//
#include <hip/hip_runtime.h>

// Geometry fixed by the reference: x [B=2, C=64, R_rot=6, charts=5, H=128, W=256] fp32.
#define RROT   6
#define CHARTS 5
#define HDIM   128
#define WDIM   256

#define CHART_STRIDE 32768LL                 // H*W
#define ROT_STRIDE   163840LL                // 5*CHART_STRIDE
#define BC_STRIDE    983040LL                // 6*ROT_STRIDE

// Fused streaming copy + pole fix. One float4 granule per loop step.
// Within each chart (8192 granules), granule 0 holds pole1 (elem 0) and
// granule 32 holds pole2 (elem 0 = col 128). For those rare granules the
// owning thread computes the 6-rot x 5-neighbor mean inline from the input.
__global__ __launch_bounds__(256) void smooth_vertices_fused(
        const float4* __restrict__ x4, float4* __restrict__ out4,
        long long n4, const float* __restrict__ x) {
    long long stride = (long long)gridDim.x * blockDim.x;
    for (long long g = (long long)blockIdx.x * blockDim.x + threadIdx.x;
         g < n4; g += stride) {
        float4 v = x4[g];
        long long gic = g & 8191;  // granule index within chart
        if (gic == 0 || gic == 32) {
            long long chart_g = g >> 13;        // global chart index
            int c = (int)(chart_g % CHARTS);
            long long bc = chart_g / (CHARTS * RROT);
            int cm = (c + CHARTS - 1) % CHARTS;
            const float* base = x + bc * BC_STRIDE;
            float s = 0.0f;
            if (gic == 0) {
                // V1 neighbors of pole (0,0): [c,1,0],[c,1,1],[c,0,1],[cm,127,128],[cm,127,127]
                #pragma unroll
                for (int r = 0; r < RROT; ++r) {
                    const float* rb = base + r * ROT_STRIDE;
                    s += rb[c  * CHART_STRIDE + 256]
                       + rb[c  * CHART_STRIDE + 257]
                       + rb[c  * CHART_STRIDE + 1]
                       + rb[cm * CHART_STRIDE + 32640]   // 127*256+128
                       + rb[cm * CHART_STRIDE + 32639];  // 127*256+127
                }
            } else {
                // V2 neighbors of pole (0,128): [c,1,128],[c,1,129],[c,0,129],[cm,127,255],[c,0,127]
                #pragma unroll
                for (int r = 0; r < RROT; ++r) {
                    const float* rb = base + r * ROT_STRIDE;
                    s += rb[c  * CHART_STRIDE + 384]
                       + rb[c  * CHART_STRIDE + 385]
                       + rb[c  * CHART_STRIDE + 129]
                       + rb[cm * CHART_STRIDE + 32767]   // 127*256+255
                       + rb[c  * CHART_STRIDE + 127];
                }
            }
            v.x = s * (1.0f / 30.0f);
        }
        out4[g] = v;
    }
}

extern "C" void kernel_launch(void* const* d_in, const int* in_sizes, int n_in,
                              void* d_out, int out_size, void* d_ws, size_t ws_size,
                              hipStream_t stream) {
    const float* x = (const float*)d_in[0];
    float* out = (float*)d_out;
    long long n4 = (long long)in_sizes[0] / 4;   // 31,457,280 granules

    int threads = 256;
    int blocks = 2048;  // 8 blocks/CU on 256 CUs; grid-stride covers the rest
    smooth_vertices_fused<<<blocks, threads, 0, stream>>>(
        (const float4*)x, (float4*)out, n4, x);
}

// Round 3
// 179.903 us; speedup vs baseline: 1.7121x; 1.7121x over previous
//
#include <hip/hip_runtime.h>

// Geometry fixed by the reference: x [B=2, C=64, R_rot=6, charts=5, H=128, W=256] fp32.
#define RROT   6
#define CHARTS 5
#define CHART_STRIDE 32768LL                 // H*W = 128*256
#define ROT_STRIDE   163840LL                // 5*CHART_STRIDE
#define BC_STRIDE    983040LL                // 6*ROT_STRIDE

typedef float f4 __attribute__((ext_vector_type(4)));

// Pure streaming copy: each block step covers 1024 float4 granules (16 KB).
// Per thread: 4 independent nontemporal loads, then 4 nontemporal stores —
// maximizes outstanding VMEM ops so we're BW-bound, not latency-bound.
__global__ __launch_bounds__(256) void copy_bulk(const f4* __restrict__ in,
                                                 f4* __restrict__ out,
                                                 long long n4) {
    const int t = threadIdx.x;
    const long long n_steps = n4 >> 10;               // granules / 1024
    for (long long s = blockIdx.x; s < n_steps; s += gridDim.x) {
        long long b = (s << 10) + t;
        f4 v0 = __builtin_nontemporal_load(&in[b]);
        f4 v1 = __builtin_nontemporal_load(&in[b + 256]);
        f4 v2 = __builtin_nontemporal_load(&in[b + 512]);
        f4 v3 = __builtin_nontemporal_load(&in[b + 768]);
        __builtin_nontemporal_store(v0, &out[b]);
        __builtin_nontemporal_store(v1, &out[b + 256]);
        __builtin_nontemporal_store(v2, &out[b + 512]);
        __builtin_nontemporal_store(v3, &out[b + 768]);
    }
    // Tail (n4 % 1024 granules) — empty for this problem, kept for safety.
    long long tail = n_steps << 10;
    long long stride = (long long)gridDim.x * blockDim.x;
    for (long long g = tail + (long long)blockIdx.x * blockDim.x + t; g < n4; g += stride)
        out[g] = in[g];
}

// One thread per (bc, chart): compute both pole means (6 rot x 5 neighbors)
// from the INPUT and overwrite the 12 pole entries in out. Runs after the
// copy on the same stream, so ordering is guaranteed.
__global__ void pole_fix(const float* __restrict__ x,
                         float* __restrict__ out, int total) {
    int idx = blockIdx.x * blockDim.x + threadIdx.x;
    if (idx >= total) return;
    int c  = idx % CHARTS;
    int bc = idx / CHARTS;
    int cm = (c + CHARTS - 1) % CHARTS;

    const float* base = x + (long long)bc * BC_STRIDE;

    // V1 neighbors of pole (0,0): [c,1,0],[c,1,1],[c,0,1],[cm,127,128],[cm,127,127]
    const long long off1[5] = {
        c  * CHART_STRIDE + 256, c * CHART_STRIDE + 257, c * CHART_STRIDE + 1,
        cm * CHART_STRIDE + 32640, cm * CHART_STRIDE + 32639,
    };
    // V2 neighbors of pole (0,128): [c,1,128],[c,1,129],[c,0,129],[cm,127,255],[c,0,127]
    const long long off2[5] = {
        c  * CHART_STRIDE + 384, c * CHART_STRIDE + 385, c * CHART_STRIDE + 129,
        cm * CHART_STRIDE + 32767, c * CHART_STRIDE + 127,
    };

    float s1 = 0.0f, s2 = 0.0f;
    #pragma unroll
    for (int r = 0; r < RROT; ++r) {
        const float* rb = base + r * ROT_STRIDE;
        #pragma unroll
        for (int n = 0; n < 5; ++n) {
            s1 += rb[off1[n]];
            s2 += rb[off2[n]];
        }
    }
    float m1 = s1 * (1.0f / 30.0f);
    float m2 = s2 * (1.0f / 30.0f);

    float* obase = out + (long long)bc * BC_STRIDE + (long long)c * CHART_STRIDE;
    #pragma unroll
    for (int r = 0; r < RROT; ++r) {
        obase[r * ROT_STRIDE + 0]   = m1;
        obase[r * ROT_STRIDE + 128] = m2;
    }
}

extern "C" void kernel_launch(void* const* d_in, const int* in_sizes, int n_in,
                              void* d_out, int out_size, void* d_ws, size_t ws_size,
                              hipStream_t stream) {
    const float* x = (const float*)d_in[0];
    float* out = (float*)d_out;
    long long n4 = (long long)in_sizes[0] / 4;   // 31,457,280 granules

    copy_bulk<<<2048, 256, 0, stream>>>((const f4*)x, (f4*)out, n4);

    int bc = (int)((long long)in_sizes[0] / BC_STRIDE);  // 128
    int total = bc * CHARTS;                              // 640
    pole_fix<<<(total + 127) / 128, 128, 0, stream>>>(x, out, total);
}